// Round 1
// baseline (2246.575 us; speedup 1.0000x reference)
//
#include <hip/hip_runtime.h>

#define SDIM 2048
#define DDIM 128
#define NBH  64
#define BR   128   // q rows per block (4 waves x 32)
#define BC   64    // keys per tile
#define KSTRIDE 136  // bf16 elems; conflict-free b128 B-frag reads
#define VSTRIDE 130  // bf16 elems; conflict-free u16 B-frag gather
#define PSTRIDE 72   // bf16 elems; conflict-free b128 A-frag reads

using bf16x8 = __attribute__((ext_vector_type(8))) short;
using f32x4  = __attribute__((ext_vector_type(4))) float;

static __device__ __forceinline__ short f2bf(float x) {
    unsigned u = __float_as_uint(x);
    u += 0x7fff + ((u >> 16) & 1);   // RNE
    return (short)(u >> 16);
}
static __device__ __forceinline__ unsigned pack2(float a, float b) {
    return ((unsigned)(unsigned short)f2bf(a)) |
           (((unsigned)(unsigned short)f2bf(b)) << 16);
}

__global__ __launch_bounds__(256, 2) void fattn_kernel(
    const float* __restrict__ Q, const float* __restrict__ K,
    const float* __restrict__ V, const float* __restrict__ M,
    float* __restrict__ O)
{
    const int qt   = blockIdx.x;          // 0..15
    const int bh   = blockIdx.y;          // 0..63
    const int tid  = threadIdx.x;
    const int wave = tid >> 6;
    const int lane = tid & 63;
    const int quad = lane >> 4;
    const int n16  = lane & 15;
    const int q0   = qt * BR;

    const float* Qb = Q + (size_t)bh * SDIM * DDIM;
    const float* Kb = K + (size_t)bh * SDIM * DDIM;
    const float* Vb = V + (size_t)bh * SDIM * DDIM;
    const float* Mb = M + (size_t)bh * SDIM * SDIM;
    float*       Ob = O + (size_t)bh * SDIM * DDIM;

    __shared__ __align__(16) unsigned short Ks[BC * KSTRIDE];
    __shared__ __align__(16) unsigned short Vs[BC * VSTRIDE];
    __shared__ __align__(16) unsigned short Ps[4][32 * PSTRIDE];

    // ---- Q A-fragments (pre-scaled by 1/sqrt(D)), kept in regs all kernel ----
    const float scale = 0.08838834764831845f;
    bf16x8 qf[2][4];
#pragma unroll
    for (int rt = 0; rt < 2; ++rt) {
        int row = q0 + wave * 32 + rt * 16 + n16;     // A: m = lane&15
        const float* qp = Qb + (size_t)row * DDIM + quad * 8;
#pragma unroll
        for (int dt = 0; dt < 4; ++dt) {              // k = dt*32 + quad*8 + j
            const float* p = qp + dt * 32;
            float4 a = *(const float4*)p;
            float4 b = *(const float4*)(p + 4);
            bf16x8 f;
            f[0] = f2bf(a.x * scale); f[1] = f2bf(a.y * scale);
            f[2] = f2bf(a.z * scale); f[3] = f2bf(a.w * scale);
            f[4] = f2bf(b.x * scale); f[5] = f2bf(b.y * scale);
            f[6] = f2bf(b.z * scale); f[7] = f2bf(b.w * scale);
            qf[rt][dt] = f;
        }
    }

    // ---- online-softmax state ----
    f32x4 acc[2][8];
    const f32x4 zero4 = {0.f, 0.f, 0.f, 0.f};
#pragma unroll
    for (int rt = 0; rt < 2; ++rt)
#pragma unroll
        for (int nt = 0; nt < 8; ++nt) acc[rt][nt] = zero4;
    float mrow[2][4], lrow[2][4];
#pragma unroll
    for (int rt = 0; rt < 2; ++rt)
#pragma unroll
        for (int r = 0; r < 4; ++r) { mrow[rt][r] = -1e30f; lrow[rt][r] = 0.f; }

    const int srow = tid >> 4;          // staging: 16 rows / pass
    const int sd0  = (tid & 15) * 8;    // 8 contiguous d per thread

    for (int k0 = 0; k0 < SDIM; k0 += BC) {
        __syncthreads();   // Ks/Vs free (prev iter reads done)

        // ---- stage K,V tile: fp32 -> bf16, coalesced 32B/thread/row ----
#pragma unroll
        for (int p = 0; p < 4; ++p) {
            int key = p * 16 + srow;
            const float* kp = Kb + (size_t)(k0 + key) * DDIM + sd0;
            const float* vp = Vb + (size_t)(k0 + key) * DDIM + sd0;
            float4 ka = *(const float4*)kp;
            float4 kb = *(const float4*)(kp + 4);
            float4 va = *(const float4*)vp;
            float4 vb = *(const float4*)(vp + 4);
            bf16x8 kw;
            kw[0] = f2bf(ka.x); kw[1] = f2bf(ka.y); kw[2] = f2bf(ka.z); kw[3] = f2bf(ka.w);
            kw[4] = f2bf(kb.x); kw[5] = f2bf(kb.y); kw[6] = f2bf(kb.z); kw[7] = f2bf(kb.w);
            *(bf16x8*)(&Ks[key * KSTRIDE + sd0]) = kw;
            unsigned* vd = (unsigned*)(&Vs[key * VSTRIDE + sd0]); // 4B-aligned
            vd[0] = pack2(va.x, va.y);
            vd[1] = pack2(va.z, va.w);
            vd[2] = pack2(vb.x, vb.y);
            vd[3] = pack2(vb.z, vb.w);
        }
        __syncthreads();

        // ---- S = Q K^T  (B-frag: B[k=d][n=key] contiguous-in-d b128) ----
        f32x4 s[2][4];
#pragma unroll
        for (int rt = 0; rt < 2; ++rt)
#pragma unroll
            for (int ct = 0; ct < 4; ++ct) s[rt][ct] = zero4;
#pragma unroll
        for (int dt = 0; dt < 4; ++dt) {
#pragma unroll
            for (int ct = 0; ct < 4; ++ct) {
                bf16x8 bf = *(const bf16x8*)(&Ks[(ct * 16 + n16) * KSTRIDE + dt * 32 + quad * 8]);
                s[0][ct] = __builtin_amdgcn_mfma_f32_16x16x32_bf16(qf[0][dt], bf, s[0][ct], 0, 0, 0);
                s[1][ct] = __builtin_amdgcn_mfma_f32_16x16x32_bf16(qf[1][dt], bf, s[1][ct], 0, 0, 0);
            }
        }

        // ---- mask add + online softmax (C layout: row=quad*4+r, col=lane&15) ----
#pragma unroll
        for (int rt = 0; rt < 2; ++rt) {
            int rowb = q0 + wave * 32 + rt * 16 + quad * 4;
#pragma unroll
            for (int ct = 0; ct < 4; ++ct) {
                const float* mp = Mb + (size_t)rowb * SDIM + k0 + ct * 16 + n16;
#pragma unroll
                for (int r = 0; r < 4; ++r)
                    s[rt][ct][r] += mp[r * SDIM];
            }
#pragma unroll
            for (int r = 0; r < 4; ++r) {
                float mx = fmaxf(fmaxf(s[rt][0][r], s[rt][1][r]),
                                 fmaxf(s[rt][2][r], s[rt][3][r]));
                mx = fmaxf(mx, __shfl_xor(mx, 1));
                mx = fmaxf(mx, __shfl_xor(mx, 2));
                mx = fmaxf(mx, __shfl_xor(mx, 4));
                mx = fmaxf(mx, __shfl_xor(mx, 8));
                float mnew = fmaxf(mrow[rt][r], mx);
                float al   = exp2f((mrow[rt][r] - mnew) * 1.44269504f);
                mrow[rt][r] = mnew;
                float rs = 0.f;
#pragma unroll
                for (int ct = 0; ct < 4; ++ct) {
                    float pv = exp2f((s[rt][ct][r] - mnew) * 1.44269504f);
                    s[rt][ct][r] = pv;
                    rs += pv;
                }
                rs += __shfl_xor(rs, 1);
                rs += __shfl_xor(rs, 2);
                rs += __shfl_xor(rs, 4);
                rs += __shfl_xor(rs, 8);
                lrow[rt][r] = lrow[rt][r] * al + rs;
                // rescale O for this row
#pragma unroll
                for (int nt = 0; nt < 8; ++nt) acc[rt][nt][r] *= al;
            }
            // ---- P: C-layout regs -> LDS (row-major, stride 72) ----
#pragma unroll
            for (int ct = 0; ct < 4; ++ct)
#pragma unroll
                for (int r = 0; r < 4; ++r)
                    Ps[wave][(rt * 16 + quad * 4 + r) * PSTRIDE + ct * 16 + n16] =
                        (unsigned short)f2bf(s[rt][ct][r]);
        }

        __syncthreads();  // P visible (also keeps waves lockstep; each wave reads own region)

        // ---- P A-frags (contiguous b128) ----
        bf16x8 pa[2][2];
#pragma unroll
        for (int rt = 0; rt < 2; ++rt)
#pragma unroll
            for (int kt = 0; kt < 2; ++kt)
                pa[rt][kt] = *(const bf16x8*)(&Ps[wave][(rt * 16 + n16) * PSTRIDE + kt * 32 + quad * 8]);

        // ---- O += P V  (V B-frag: u16 gather, stride 130 => conflict-free) ----
#pragma unroll
        for (int nt = 0; nt < 8; ++nt) {
            bf16x8 vb0, vb1;
#pragma unroll
            for (int j = 0; j < 8; ++j) {
                vb0[j] = (short)Vs[(quad * 8 + j) * VSTRIDE + nt * 16 + n16];
                vb1[j] = (short)Vs[(32 + quad * 8 + j) * VSTRIDE + nt * 16 + n16];
            }
#pragma unroll
            for (int rt = 0; rt < 2; ++rt) {
                acc[rt][nt] = __builtin_amdgcn_mfma_f32_16x16x32_bf16(pa[rt][0], vb0, acc[rt][nt], 0, 0, 0);
                acc[rt][nt] = __builtin_amdgcn_mfma_f32_16x16x32_bf16(pa[rt][1], vb1, acc[rt][nt], 0, 0, 0);
            }
        }
    }

    // ---- epilogue: O /= l, store fp32 ----
#pragma unroll
    for (int rt = 0; rt < 2; ++rt) {
#pragma unroll
        for (int r = 0; r < 4; ++r) {
            float inv = 1.0f / lrow[rt][r];
            int row = q0 + wave * 32 + rt * 16 + quad * 4 + r;
            float* op = Ob + (size_t)row * DDIM + n16;
#pragma unroll
            for (int nt = 0; nt < 8; ++nt)
                op[nt * 16] = acc[rt][nt][r] * inv;
        }
    }
}

extern "C" void kernel_launch(void* const* d_in, const int* in_sizes, int n_in,
                              void* d_out, int out_size, void* d_ws, size_t ws_size,
                              hipStream_t stream) {
    const float* Q = (const float*)d_in[0];
    const float* K = (const float*)d_in[1];
    const float* V = (const float*)d_in[2];
    const float* M = (const float*)d_in[3];
    float* O = (float*)d_out;
    dim3 grid(SDIM / BR, NBH);
    fattn_kernel<<<grid, 256, 0, stream>>>(Q, K, V, M, O);
}

// Round 2
// 1953.131 us; speedup vs baseline: 1.1502x; 1.1502x over previous
//
#include <hip/hip_runtime.h>

#define SDIM 2048
#define DDIM 128
#define NBH  64
#define BR   128   // q rows per block (4 waves x 32)
#define BC   64    // keys per tile
#define PSTRIDE 72 // bf16 elems; conflict-free b128 A-frag reads of P

using bf16x8 = __attribute__((ext_vector_type(8))) short;
using f32x4  = __attribute__((ext_vector_type(4))) float;

static __device__ __forceinline__ short f2bf(float x) {
    unsigned u = __float_as_uint(x);
    u += 0x7fff + ((u >> 16) & 1);   // RNE
    return (short)(u >> 16);
}
static __device__ __forceinline__ unsigned pack2(float a, float b) {
    return ((unsigned)(unsigned short)f2bf(a)) |
           (((unsigned)(unsigned short)f2bf(b)) << 16);
}

// ---- prep 1: K fp32 -> bf16 (elementwise) ----
__global__ __launch_bounds__(256) void kconv_kernel(const float* __restrict__ K,
                                                    unsigned short* __restrict__ Kc)
{
    size_t i = ((size_t)blockIdx.x * 256 + threadIdx.x) * 4;
    float4 v = *(const float4*)(K + i);
    uint2 o;
    o.x = pack2(v.x, v.y);
    o.y = pack2(v.z, v.w);
    *(uint2*)(Kc + i) = o;
}

// ---- prep 2: V fp32 [bh][s][d] -> bf16 V^T [bh][d][s] ----
__global__ __launch_bounds__(256) void vtrans_kernel(const float* __restrict__ V,
                                                     unsigned short* __restrict__ Vt)
{
    __shared__ float t[32][33];
    const int bh = blockIdx.z;
    const int s0 = blockIdx.x * 32;
    const int d0 = blockIdx.y * 32;
    const int x = threadIdx.x & 31;
    const int y = threadIdx.x >> 5;
    const float* Vb = V + (size_t)bh * SDIM * DDIM;
    unsigned short* Vtb = Vt + (size_t)bh * SDIM * DDIM;
#pragma unroll
    for (int i = 0; i < 4; ++i) {
        int r = y + i * 8;
        t[r][x] = Vb[(size_t)(s0 + r) * DDIM + d0 + x];
    }
    __syncthreads();
#pragma unroll
    for (int i = 0; i < 4; ++i) {
        int r = y + i * 8;
        Vtb[(size_t)(d0 + r) * SDIM + s0 + x] = (unsigned short)f2bf(t[x][r]);
    }
}

// ---- main: flash attention, K/V frags straight from global bf16, no barriers ----
__global__ __launch_bounds__(256, 2) void fattn_kernel(
    const float* __restrict__ Q, const float* __restrict__ M,
    const unsigned short* __restrict__ Kc, const unsigned short* __restrict__ Vt,
    float* __restrict__ O)
{
    const int qt   = blockIdx.x;
    const int bh   = blockIdx.y;
    const int tid  = threadIdx.x;
    const int wave = tid >> 6;
    const int lane = tid & 63;
    const int quad = lane >> 4;
    const int n16  = lane & 15;
    const int q0   = qt * BR;

    const float* Qb = Q + (size_t)bh * SDIM * DDIM;
    const float* Mb = M + (size_t)bh * SDIM * SDIM;
    const unsigned short* Kb = Kc + (size_t)bh * SDIM * DDIM;  // [s][d] bf16
    const unsigned short* Vb = Vt + (size_t)bh * SDIM * DDIM;  // [d][s] bf16
    float* Ob = O + (size_t)bh * SDIM * DDIM;

    __shared__ __align__(16) unsigned short Ps[4][32 * PSTRIDE];

    // Q A-fragments, pre-scaled, in regs for the whole kernel
    const float scale = 0.08838834764831845f;
    bf16x8 qf[2][4];
#pragma unroll
    for (int rt = 0; rt < 2; ++rt) {
        int row = q0 + wave * 32 + rt * 16 + n16;
        const float* qp = Qb + (size_t)row * DDIM + quad * 8;
#pragma unroll
        for (int dt = 0; dt < 4; ++dt) {
            const float* p = qp + dt * 32;
            float4 a = *(const float4*)p;
            float4 b = *(const float4*)(p + 4);
            bf16x8 f;
            f[0] = f2bf(a.x * scale); f[1] = f2bf(a.y * scale);
            f[2] = f2bf(a.z * scale); f[3] = f2bf(a.w * scale);
            f[4] = f2bf(b.x * scale); f[5] = f2bf(b.y * scale);
            f[6] = f2bf(b.z * scale); f[7] = f2bf(b.w * scale);
            qf[rt][dt] = f;
        }
    }

    f32x4 acc[2][8];
    const f32x4 zero4 = {0.f, 0.f, 0.f, 0.f};
#pragma unroll
    for (int rt = 0; rt < 2; ++rt)
#pragma unroll
        for (int nt = 0; nt < 8; ++nt) acc[rt][nt] = zero4;
    float mrow[2][4], lrow[2][4];
#pragma unroll
    for (int rt = 0; rt < 2; ++rt)
#pragma unroll
        for (int r = 0; r < 4; ++r) { mrow[rt][r] = -1e30f; lrow[rt][r] = 0.f; }

    for (int k0 = 0; k0 < SDIM; k0 += BC) {
        // ---- mask prefetch (32 scalar loads, covered by QK^T below) ----
        float mk[2][4][4];
#pragma unroll
        for (int rt = 0; rt < 2; ++rt) {
            int rowb = q0 + wave * 32 + rt * 16 + quad * 4;
            const float* mpb = Mb + (size_t)rowb * SDIM + k0 + n16;
#pragma unroll
            for (int ct = 0; ct < 4; ++ct)
#pragma unroll
                for (int r = 0; r < 4; ++r)
                    mk[rt][ct][r] = mpb[(size_t)r * SDIM + ct * 16];
        }

        // ---- S = Q K^T : B-frags (K[key][d], contiguous in d) from global ----
        f32x4 s[2][4];
#pragma unroll
        for (int rt = 0; rt < 2; ++rt)
#pragma unroll
            for (int ct = 0; ct < 4; ++ct) s[rt][ct] = zero4;
#pragma unroll
        for (int dt = 0; dt < 4; ++dt) {
#pragma unroll
            for (int ct = 0; ct < 4; ++ct) {
                bf16x8 kf = *(const bf16x8*)(Kb + (size_t)(k0 + ct * 16 + n16) * DDIM + dt * 32 + quad * 8);
                s[0][ct] = __builtin_amdgcn_mfma_f32_16x16x32_bf16(qf[0][dt], kf, s[0][ct], 0, 0, 0);
                s[1][ct] = __builtin_amdgcn_mfma_f32_16x16x32_bf16(qf[1][dt], kf, s[1][ct], 0, 0, 0);
            }
        }

        // ---- mask add ----
#pragma unroll
        for (int rt = 0; rt < 2; ++rt)
#pragma unroll
            for (int ct = 0; ct < 4; ++ct)
#pragma unroll
                for (int r = 0; r < 4; ++r)
                    s[rt][ct][r] += mk[rt][ct][r];

        // ---- online softmax: batched shuffle chains (8 independent rows) ----
        float mx[2][4];
#pragma unroll
        for (int rt = 0; rt < 2; ++rt)
#pragma unroll
            for (int r = 0; r < 4; ++r)
                mx[rt][r] = fmaxf(fmaxf(s[rt][0][r], s[rt][1][r]),
                                  fmaxf(s[rt][2][r], s[rt][3][r]));
#pragma unroll
        for (int st = 1; st <= 8; st <<= 1)
#pragma unroll
            for (int rt = 0; rt < 2; ++rt)
#pragma unroll
                for (int r = 0; r < 4; ++r)
                    mx[rt][r] = fmaxf(mx[rt][r], __shfl_xor(mx[rt][r], st));

        float al[2][4], rs[2][4];
#pragma unroll
        for (int rt = 0; rt < 2; ++rt)
#pragma unroll
            for (int r = 0; r < 4; ++r) {
                float mnew = fmaxf(mrow[rt][r], mx[rt][r]);
                al[rt][r] = exp2f((mrow[rt][r] - mnew) * 1.44269504f);
                mrow[rt][r] = mnew;
                float t = 0.f;
#pragma unroll
                for (int ct = 0; ct < 4; ++ct) {
                    float pv = exp2f((s[rt][ct][r] - mnew) * 1.44269504f);
                    s[rt][ct][r] = pv;
                    t += pv;
                }
                rs[rt][r] = t;
            }
#pragma unroll
        for (int st = 1; st <= 8; st <<= 1)
#pragma unroll
            for (int rt = 0; rt < 2; ++rt)
#pragma unroll
                for (int r = 0; r < 4; ++r)
                    rs[rt][r] += __shfl_xor(rs[rt][r], st);
#pragma unroll
        for (int rt = 0; rt < 2; ++rt)
#pragma unroll
            for (int r = 0; r < 4; ++r) {
                lrow[rt][r] = lrow[rt][r] * al[rt][r] + rs[rt][r];
#pragma unroll
                for (int nt = 0; nt < 8; ++nt) acc[rt][nt][r] *= al[rt][r];
            }

        // ---- P: C-layout regs -> LDS (own wave region; no barrier needed) ----
#pragma unroll
        for (int rt = 0; rt < 2; ++rt)
#pragma unroll
            for (int ct = 0; ct < 4; ++ct)
#pragma unroll
                for (int r = 0; r < 4; ++r)
                    Ps[wave][(rt * 16 + (lane >> 4) * 4 + r) * PSTRIDE + ct * 16 + n16] =
                        (unsigned short)f2bf(s[rt][ct][r]);

        // ---- P A-frags (lgkmcnt ordering within wave suffices) ----
        bf16x8 pa[2][2];
#pragma unroll
        for (int rt = 0; rt < 2; ++rt)
#pragma unroll
            for (int kt = 0; kt < 2; ++kt)
                pa[rt][kt] = *(const bf16x8*)(&Ps[wave][(rt * 16 + n16) * PSTRIDE + kt * 32 + quad * 8]);

        // ---- O += P V : B-frags (V^T[d][s], contiguous in s) from global ----
#pragma unroll
        for (int nt = 0; nt < 8; ++nt) {
#pragma unroll
            for (int kt = 0; kt < 2; ++kt) {
                bf16x8 vf = *(const bf16x8*)(Vb + (size_t)(nt * 16 + n16) * SDIM + k0 + kt * 32 + quad * 8);
                acc[0][nt] = __builtin_amdgcn_mfma_f32_16x16x32_bf16(pa[0][kt], vf, acc[0][nt], 0, 0, 0);
                acc[1][nt] = __builtin_amdgcn_mfma_f32_16x16x32_bf16(pa[1][kt], vf, acc[1][nt], 0, 0, 0);
            }
        }
    }

    // ---- epilogue ----
#pragma unroll
    for (int rt = 0; rt < 2; ++rt) {
#pragma unroll
        for (int r = 0; r < 4; ++r) {
            float inv = 1.0f / lrow[rt][r];
            int row = q0 + wave * 32 + rt * 16 + quad * 4 + r;
            float* op = Ob + (size_t)row * DDIM + n16;
#pragma unroll
            for (int nt = 0; nt < 8; ++nt)
                op[nt * 16] = acc[rt][nt][r] * inv;
        }
    }
}

extern "C" void kernel_launch(void* const* d_in, const int* in_sizes, int n_in,
                              void* d_out, int out_size, void* d_ws, size_t ws_size,
                              hipStream_t stream) {
    const float* Q = (const float*)d_in[0];
    const float* K = (const float*)d_in[1];
    const float* V = (const float*)d_in[2];
    const float* M = (const float*)d_in[3];
    float* O = (float*)d_out;

    unsigned short* Kc = (unsigned short*)d_ws;
    unsigned short* Vt = Kc + (size_t)NBH * SDIM * DDIM;

    // prep: K -> bf16, V -> bf16 transposed
    size_t nElem = (size_t)NBH * SDIM * DDIM;            // 16.7M
    kconv_kernel<<<dim3(nElem / (256 * 4)), 256, 0, stream>>>(K, Kc);
    vtrans_kernel<<<dim3(SDIM / 32, DDIM / 32, NBH), 256, 0, stream>>>(V, Vt);

    dim3 grid(SDIM / BR, NBH);
    fattn_kernel<<<grid, 256, 0, stream>>>(Q, M, Kc, Vt, O);
}